// Round 14
// baseline (358.034 us; speedup 1.0000x reference)
//
#include <hip/hip_runtime.h>

#define B_ 4
#define S_ 2048
#define D_ 1024
#define H_ 16
#define DK_ 64
#define M_ (B_*S_)   // 8192 rows
#define K_ D_        // 1024
#define N_ D_        // 1024
#define NSTEP 32     // K_/32

typedef unsigned short u16;
typedef unsigned int u32;
typedef __bf16 bf16x8 __attribute__((ext_vector_type(8)));
typedef float f32x4 __attribute__((ext_vector_type(4)));
typedef u32 u32x4v __attribute__((ext_vector_type(4)));

// native 2^x (v_exp_f32); '__exp2f' collides with glibc math.h macros
#define EXP2F(x) __builtin_amdgcn_exp2f(x)

__device__ __forceinline__ u16 f2bf(float f) {
    u32 u = __builtin_bit_cast(u32, f);
    u += 0x7fff + ((u >> 16) & 1);   // round-to-nearest-even
    return (u16)(u >> 16);
}
__device__ __forceinline__ float bf2f(u16 h) {
    u32 u = ((u32)h) << 16;
    return __builtin_bit_cast(float, u);
}
// truncation-packed bf16 pair (3 ops; P >= 0 -> bias < 2^-8 rel, OK for P)
__device__ __forceinline__ u32 pack_trunc(float a, float b) {
    return (__builtin_bit_cast(u32, a) >> 16) | (__builtin_bit_cast(u32, b) & 0xffff0000u);
}

#define GLDS16(g, l) __builtin_amdgcn_global_load_lds( \
    (__attribute__((address_space(1))) void*)(g),      \
    (__attribute__((address_space(3))) void*)(l), 16, 0, 0)

// ---------------------------------------------------------------------------
// fp32 -> bf16 convert, ALL 5 tensors in one dispatch (x + 4 weights).
// ---------------------------------------------------------------------------
__global__ __launch_bounds__(256) void cvt_all(
    const float* __restrict__ x,
    const float* __restrict__ w0, const float* __restrict__ w1,
    const float* __restrict__ w2, const float* __restrict__ w3,
    u16* __restrict__ xb,
    u16* __restrict__ o0, u16* __restrict__ o1,
    u16* __restrict__ o2, u16* __restrict__ o3) {
    const size_t i = (size_t)blockIdx.x * 256 + threadIdx.x;
    const float* in;
    u16* out;
    size_t off;
    if (i < 2097152) {
        in = x; out = xb; off = i;
    } else {
        const size_t j = i - 2097152;
        const int wi = (int)(j >> 18);
        off = j & 262143;
        in  = (wi == 0) ? w0 : (wi == 1) ? w1 : (wi == 2) ? w2 : w3;
        out = (wi == 0) ? o0 : (wi == 1) ? o1 : (wi == 2) ? o2 : o3;
    }
    const float4 f = *(const float4*)(in + off * 4);
    u32 p0 = (u32)f2bf(f.x) | ((u32)f2bf(f.y) << 16);
    u32 p1 = (u32)f2bf(f.z) | ((u32)f2bf(f.w) << 16);
    *(uint2*)(out + off * 4) = make_uint2(p0, p1);
}

// ---------------------------------------------------------------------------
// GEMM inner (3-buffer depth-2 counted-vmcnt, R7/R11 structure — best
// measured: 71.4-73.3us qkv; the 256² 8-phase port measured 79.7 (R13) due
// to 1-block/CU residency with a 1.5-round grid -> shelved).
// Per step t: vmcnt(4) [stage(t) landed, stage(t+1) in flight] ->
// lgkmcnt(0) -> s_barrier -> issue stage(t+2) -> ds_read+MFMA buf[t%3].
// (kept: chunk XOR swizzle both-sides, T5 setprio)
// MODE 0: bf16 C.  MODE 1: fp32 C.  MODE 2: bf16 V-transposed store.
// ---------------------------------------------------------------------------
template <int MODE>
__device__ __forceinline__ void gemm_tile3(const u16* __restrict__ A,
                                           const u16* __restrict__ Bm,
                                           void* __restrict__ Cv,
                                           int m0, int n0,
                                           u16* __restrict__ As,
                                           u16* __restrict__ Bs) {
    const int tid  = threadIdx.x;
    const int wave = tid >> 6, lane = tid & 63;
    const int wm = wave & 1, wn = wave >> 1;
    const int quad = lane >> 4, mcol = lane & 15;

    const int c0 = wave, c1 = wave + 4;
    const int r0 = c0 * 16 + (lane >> 2), r1 = c1 * 16 + (lane >> 2);
    const int kb = (((lane & 3) ^ ((lane >> 3) & 3)) * 8);   // pre-swizzled src chunk
    const u16* ga0 = A  + (size_t)(m0 + r0) * K_ + kb;
    const u16* ga1 = A  + (size_t)(m0 + r1) * K_ + kb;
    const u16* gb0 = Bm + (size_t)(n0 + r0) * K_ + kb;
    const u16* gb1 = Bm + (size_t)(n0 + r1) * K_ + kb;
    const int lo0 = c0 * 512, lo1 = c1 * 512;
    const int rsw = ((mcol >> 1) & 3);   // read-side chunk XOR

    f32x4 acc[4][4];
#pragma unroll
    for (int i = 0; i < 4; i++)
#pragma unroll
        for (int j = 0; j < 4; j++) acc[i][j] = f32x4{0.f, 0.f, 0.f, 0.f};

    // prologue: stage(0) -> buf0, stage(1) -> buf1 (8 loads in flight)
    GLDS16(ga0, As + lo0); GLDS16(ga1, As + lo1);
    GLDS16(gb0, Bs + lo0); GLDS16(gb1, Bs + lo1);
    ga0 += 32; ga1 += 32; gb0 += 32; gb1 += 32;
    GLDS16(ga0, As + 4096 + lo0); GLDS16(ga1, As + 4096 + lo1);
    GLDS16(gb0, Bs + 4096 + lo0); GLDS16(gb1, Bs + 4096 + lo1);
    ga0 += 32; ga1 += 32; gb0 += 32; gb1 += 32;

    int cur = 0, tgt = 2;
    for (int t = 0; t < NSTEP; ++t) {
        if (t < NSTEP - 1) asm volatile("s_waitcnt vmcnt(4)" ::: "memory");
        else               asm volatile("s_waitcnt vmcnt(0)" ::: "memory");
        asm volatile("s_waitcnt lgkmcnt(0)" ::: "memory");
        __builtin_amdgcn_s_barrier();

        if (t < NSTEP - 2) {
            u16* at = As + tgt * 4096;
            u16* bt = Bs + tgt * 4096;
            GLDS16(ga0, at + lo0); GLDS16(ga1, at + lo1);
            GLDS16(gb0, bt + lo0); GLDS16(gb1, bt + lo1);
            ga0 += 32; ga1 += 32; gb0 += 32; gb1 += 32;
        }

        const u16* Ab = As + cur * 4096;
        const u16* Bb = Bs + cur * 4096;
        bf16x8 af[4], bfr[4];
#pragma unroll
        for (int i = 0; i < 4; i++) {
            af[i]  = *(const bf16x8*)&Ab[(wm * 64 + i * 16 + mcol) * 32 + (quad ^ rsw) * 8];
            bfr[i] = *(const bf16x8*)&Bb[(wn * 64 + i * 16 + mcol) * 32 + (quad ^ rsw) * 8];
        }
        __builtin_amdgcn_s_setprio(1);
#pragma unroll
        for (int i = 0; i < 4; i++)
#pragma unroll
            for (int j = 0; j < 4; j++)
                acc[i][j] = __builtin_amdgcn_mfma_f32_16x16x32_bf16(
                    af[i], bfr[j], acc[i][j], 0, 0, 0);
        __builtin_amdgcn_s_setprio(0);

        cur = (cur == 2) ? 0 : cur + 1;
        tgt = (tgt == 2) ? 0 : tgt + 1;
    }

    // epilogue: C/D layout row=(lane>>4)*4+reg, col=lane&15
#pragma unroll
    for (int i = 0; i < 4; i++) {
        const int row = m0 + wm * 64 + i * 16 + quad * 4;
#pragma unroll
        for (int j = 0; j < 4; j++) {
            const int col = n0 + wn * 64 + j * 16 + mcol;
            if constexpr (MODE == 2) {
                const int hh = col >> 6, dd = col & 63;
                const int bb = row >> 11, ss = row & 2047;
                const u32 lo = (u32)f2bf(acc[i][j][0]) | ((u32)f2bf(acc[i][j][1]) << 16);
                const u32 hi = (u32)f2bf(acc[i][j][2]) | ((u32)f2bf(acc[i][j][3]) << 16);
                *(uint2*)((u16*)Cv + ((size_t)((bb * H_ + hh) * DK_ + dd)) * S_ + ss) =
                    make_uint2(lo, hi);
            } else {
#pragma unroll
                for (int r = 0; r < 4; r++) {
                    if constexpr (MODE == 1)
                        ((float*)Cv)[(size_t)(row + r) * N_ + col] = acc[i][j][r];
                    else
                        ((u16*)Cv)[(size_t)(row + r) * N_ + col] = f2bf(acc[i][j][r]);
                }
            }
        }
    }
}

// Q, K, V in one dispatch, flat 1536-block grid with XCD-aware remap (T1).
__global__ __launch_bounds__(256) void gemm_qkv_kernel(
    const u16* __restrict__ x,
    const u16* __restrict__ wq, const u16* __restrict__ wk,
    const u16* __restrict__ wv,
    u16* __restrict__ q, u16* __restrict__ k, u16* __restrict__ vt) {
    __shared__ u16 As[3 * 4096];
    __shared__ u16 Bs[3 * 4096];
    const int flat = blockIdx.x;
    const int w = (flat & 7) * 192 + (flat >> 3);
    const int my = w / 24;
    const int rem = w - my * 24;
    const int z = rem >> 3, nx = rem & 7;
    const int m0 = my * 128, n0 = nx * 128;
    if (z == 2) {
        gemm_tile3<2>(x, wv, vt, m0, n0, As, Bs);
    } else {
        const u16* Bm = z ? wk : wq;
        u16* C        = z ? k  : q;
        gemm_tile3<0>(x, Bm, C, m0, n0, As, Bs);
    }
}

// ---------------------------------------------------------------------------
// gemm_out: 2-phase 128², internal 32KB LDS (5 blocks/CU). Frozen.
// ---------------------------------------------------------------------------
__global__ __launch_bounds__(256) void gemm_out_kernel(
    const u16* __restrict__ o, const u16* __restrict__ wo, float* __restrict__ out) {
    __shared__ u16 As[2][128 * 32];
    __shared__ u16 Bs[2][128 * 32];
    const int flat = blockIdx.x;
    const int w = (flat & 7) * 64 + (flat >> 3);
    const int m0 = (w >> 3) * 128, n0 = (w & 7) * 128;

    const int tid  = threadIdx.x;
    const int wave = tid >> 6, lane = tid & 63;
    const int wm = wave & 1, wn = wave >> 1;
    const int quad = lane >> 4, mcol = lane & 15;

    const int c0 = wave, c1 = wave + 4;
    const int r0 = c0 * 16 + (lane >> 2), r1 = c1 * 16 + (lane >> 2);
    const int kb = (((lane & 3) ^ ((lane >> 3) & 3)) * 8);
    const u16* ga0 = o  + (size_t)(m0 + r0) * K_ + kb;
    const u16* ga1 = o  + (size_t)(m0 + r1) * K_ + kb;
    const u16* gb0 = wo + (size_t)(n0 + r0) * K_ + kb;
    const u16* gb1 = wo + (size_t)(n0 + r1) * K_ + kb;
    const int lo0 = c0 * 512, lo1 = c1 * 512;
    const int rsw = ((mcol >> 1) & 3);

    f32x4 acc[4][4];
#pragma unroll
    for (int i = 0; i < 4; i++)
#pragma unroll
        for (int j = 0; j < 4; j++) acc[i][j] = f32x4{0.f, 0.f, 0.f, 0.f};

    GLDS16(ga0, &As[0][lo0]); GLDS16(ga1, &As[0][lo1]);
    GLDS16(gb0, &Bs[0][lo0]); GLDS16(gb1, &Bs[0][lo1]);
    ga0 += 32; ga1 += 32; gb0 += 32; gb1 += 32;
    __syncthreads();

    for (int kt = 0; kt < K_; kt += 32) {
        const int cur = (kt >> 5) & 1;
        if (kt + 32 < K_) {
            const int nxt = cur ^ 1;
            GLDS16(ga0, &As[nxt][lo0]); GLDS16(ga1, &As[nxt][lo1]);
            GLDS16(gb0, &Bs[nxt][lo0]); GLDS16(gb1, &Bs[nxt][lo1]);
            ga0 += 32; ga1 += 32; gb0 += 32; gb1 += 32;
        }

        bf16x8 af[4], bfr[4];
#pragma unroll
        for (int i = 0; i < 4; i++) {
            af[i]  = *(const bf16x8*)&As[cur][(wm * 64 + i * 16 + mcol) * 32 + (quad ^ rsw) * 8];
            bfr[i] = *(const bf16x8*)&Bs[cur][(wn * 64 + i * 16 + mcol) * 32 + (quad ^ rsw) * 8];
        }
        __builtin_amdgcn_s_setprio(1);
#pragma unroll
        for (int i = 0; i < 4; i++)
#pragma unroll
            for (int j = 0; j < 4; j++)
                acc[i][j] = __builtin_amdgcn_mfma_f32_16x16x32_bf16(
                    af[i], bfr[j], acc[i][j], 0, 0, 0);
        __builtin_amdgcn_s_setprio(0);

        __syncthreads();
    }

#pragma unroll
    for (int i = 0; i < 4; i++) {
        const int row = m0 + wm * 64 + i * 16 + quad * 4;
#pragma unroll
        for (int j = 0; j < 4; j++) {
            const int col = n0 + wn * 64 + j * 16 + mcol;
#pragma unroll
            for (int r = 0; r < 4; r++)
                out[(size_t)(row + r) * N_ + col] = acc[i][j][r];
        }
    }
}

// ---------------------------------------------------------------------------
// RoPE (interleaved) in-place, vectorized (16 u16 / thread, uint4 ld/st).
// Q additionally scaled by log2(e)/8 (folds 1/sqrt(DK) + exp->exp2).
// ---------------------------------------------------------------------------
__global__ __launch_bounds__(256) void rope_qk(u16* __restrict__ q,
                                               u16* __restrict__ k,
                                               const int* __restrict__ pos) {
    const int idx = blockIdx.x * 256 + threadIdx.x;   // B*S*H*4 threads
    const int seg = idx & 3;
    const int h = (idx >> 2) & (H_ - 1);
    const int s = (idx >> 6) & (S_ - 1);
    const int b = idx >> 17;
    const float p = (float)pos[s];
    const float QSC = 0.18033688011112042f;   // log2(e)/sqrt(DK)
    const size_t off = ((size_t)(b * S_ + s)) * D_ + h * DK_ + seg * 16;

    u32 qa[8], ka[8];
    *(uint4*)&qa[0] = *(const uint4*)(q + off);
    *(uint4*)&qa[4] = *(const uint4*)(q + off + 8);
    *(uint4*)&ka[0] = *(const uint4*)(k + off);
    *(uint4*)&ka[4] = *(const uint4*)(k + off + 8);
#pragma unroll
    for (int w = 0; w < 8; w++) {
        const int i = seg * 8 + w;
        const float inv = exp2f((float)i * (-13.287712379549449f / 32.f));
        const float ang = p * inv;
        float sn, cs;
        __sincosf(ang, &sn, &cs);
        {
            const float x1 = bf2f((u16)(qa[w] & 0xffff));
            const float x2 = bf2f((u16)(qa[w] >> 16));
            qa[w] = (u32)f2bf((x1 * cs - x2 * sn) * QSC) |
                    ((u32)f2bf((x1 * sn + x2 * cs) * QSC) << 16);
        }
        {
            const float x1 = bf2f((u16)(ka[w] & 0xffff));
            const float x2 = bf2f((u16)(ka[w] >> 16));
            ka[w] = (u32)f2bf(x1 * cs - x2 * sn) |
                    ((u32)f2bf(x1 * sn + x2 * cs) << 16);
        }
    }
    *(uint4*)(q + off)     = *(uint4*)&qa[0];
    *(uint4*)(q + off + 8) = *(uint4*)&qa[4];
    *(uint4*)(k + off)     = *(uint4*)&ka[0];
    *(uint4*)(k + off + 8) = *(uint4*)&ka[4];
}

// ---------------------------------------------------------------------------
// Causal flash attention, MFMA, S^T formulation, exp2-domain softmax.
//
// R13 retry of the R5 64-row restructure WITHOUT the register cap:
//  * 128-thread blocks (2 waves), 64 q-rows; grid 2048 (32 qt x 64 bh),
//    heavy-first (qt descending, LPT). 8 blocks/CU resident: LDS 8x16KB =
//    128KB <= 160, VGPR ~108 -> 4 waves/SIMD. 16 waves/CU vs today's ~6.
//  * __launch_bounds__(128) ONLY — R5's (128,4) forced VGPR=64 and spilled
//    477MB to scratch. Body is R5's (passed refcheck), incl. ones-trick.
//  * Mask iff j==qt (wave-uniform); no fully-masked waves.
//  (kept: key-permuted LDS, XOR swizzle both-sides, setprio, defer-max,
//   MFMA ones-trick denominator)
// ---------------------------------------------------------------------------
__global__ __launch_bounds__(128) void attn_kernel(
    const u16* __restrict__ q, const u16* __restrict__ k,
    const u16* __restrict__ vt, u16* __restrict__ o) {
    __shared__ u16 Ks[64 * 64];      // [permuted key][d], XOR-swizzled
    __shared__ u16 Vs[64 * 64];      // [d][key] (natural key order), XOR-swizzled

    const int tid = threadIdx.x, wave = tid >> 6, lane = tid & 63;
    const int flat = blockIdx.x;
    const int qt = 31 - (flat >> 6);          // heavy blocks first (LPT)
    const int h = flat & (H_ - 1);
    const int b = (flat >> 4) & 3;
    const int quad = lane >> 4, mcol = lane & 15;
    const int srd = mcol & 7;                 // read-side swizzle
    const int q0 = qt * 64;
    const int wq0 = q0 + wave * 32;
    const int jmax = qt;

    // staging: thread owns row rr2 (0..63), 4 contiguous 16B chunks
    const int rr2 = tid >> 1, cc2 = tid & 1;
    const int sw = rr2 & 7;                   // write-side swizzle
    int so[4];
#pragma unroll
    for (int t = 0; t < 4; t++)
        so[t] = rr2 * 64 + (((cc2 * 4 + t) ^ sw) << 3);
    // sigma(rr2): bits [5,1,0] keep, bits[3:2]->[4:3], bit[4]->[2]
    const int prr = (rr2 & 35) | ((rr2 & 12) << 1) | ((rr2 & 16) >> 2);
    const int ch2 = cc2 * 32;
    const u16* krow = k + ((size_t)(b * S_ + prr)) * D_ + h * DK_ + ch2;
    const u16* vrow = vt + ((size_t)((b * H_ + h) * DK_ + rr2)) * S_ + ch2;

    // ones B-operand for the l row-sum MFMA (bf16 1.0 = 0x3F80)
    u32x4v onesw;
    onesw[0] = onesw[1] = onesw[2] = onesw[3] = 0x3F803F80u;
    const bf16x8 onesf = __builtin_bit_cast(bf16x8, onesw);

    // Q fragments straight from global
    bf16x8 qf[2][2];
#pragma unroll
    for (int g = 0; g < 2; g++) {
        const u16* qs = q + ((size_t)(b * S_ + wq0 + g * 16 + mcol)) * D_ + h * DK_ + quad * 8;
        qf[g][0] = *(const bf16x8*)qs;
        qf[g][1] = *(const bf16x8*)(qs + 32);
    }

    float m[2] = {-1e30f, -1e30f};
    f32x4 lacc[2];
    f32x4 oacc[2][4];
#pragma unroll
    for (int g = 0; g < 2; g++) {
        lacc[g] = f32x4{0.f, 0.f, 0.f, 0.f};
#pragma unroll
        for (int dn = 0; dn < 4; dn++) oacc[g][dn] = f32x4{0.f, 0.f, 0.f, 0.f};
    }

    uint4 kr[4], vr[4];
#pragma unroll
    for (int t = 0; t < 4; t++) {
        kr[t] = *(const uint4*)(krow + t * 8);
        vr[t] = *(const uint4*)(vrow + t * 8);
    }

    for (int j = 0; j <= jmax; j++) {
        __syncthreads();
#pragma unroll
        for (int t = 0; t < 4; t++) {
            *(uint4*)&Ks[so[t]] = kr[t];
            *(uint4*)&Vs[so[t]] = vr[t];
        }
        __syncthreads();

        if (j < jmax) {
#pragma unroll
            for (int t = 0; t < 4; t++) {
                kr[t] = *(const uint4*)(krow + (size_t)(j + 1) * 64 * D_ + t * 8);
                vr[t] = *(const uint4*)(vrow + (j + 1) * 64 + t * 8);
            }
        }

        // S^T = K.Q^T  (rows = permuted keys)
        f32x4 st[2][4];
        __builtin_amdgcn_s_setprio(1);
#pragma unroll
        for (int n = 0; n < 4; n++) {
            const u16* kl = &Ks[(n * 16 + mcol) * 64];
            bf16x8 kf0 = *(const bf16x8*)&kl[(quad ^ srd) << 3];
            bf16x8 kf1 = *(const bf16x8*)&kl[((quad | 4) ^ srd) << 3];
            f32x4 z0 = f32x4{0.f, 0.f, 0.f, 0.f};
            z0 = __builtin_amdgcn_mfma_f32_16x16x32_bf16(kf0, qf[0][0], z0, 0, 0, 0);
            z0 = __builtin_amdgcn_mfma_f32_16x16x32_bf16(kf1, qf[0][1], z0, 0, 0, 0);
            st[0][n] = z0;
            f32x4 z1 = f32x4{0.f, 0.f, 0.f, 0.f};
            z1 = __builtin_amdgcn_mfma_f32_16x16x32_bf16(kf0, qf[1][0], z1, 0, 0, 0);
            z1 = __builtin_amdgcn_mfma_f32_16x16x32_bf16(kf1, qf[1][1], z1, 0, 0, 0);
            st[1][n] = z1;
        }
        __builtin_amdgcn_s_setprio(0);

        // causal mask (only the diagonal tile):
        // st[g][n][r] is true key j*64 + 32*n1 + 8*quad + 4*n0 + r
        if (j == jmax) {
#pragma unroll
            for (int g = 0; g < 2; g++) {
                const int qg = wq0 + g * 16 + mcol;
#pragma unroll
                for (int n = 0; n < 4; n++) {
                    const int tb = j * 64 + ((n >> 1) << 5) + ((n & 1) << 2) + quad * 8;
#pragma unroll
                    for (int r = 0; r < 4; r++)
                        if (tb + r > qg) st[g][n][r] = -1e30f;
                }
            }
        }

        // online softmax, exp2 domain, defer-max; sum offloaded to MFMA
#pragma unroll
        for (int g = 0; g < 2; g++) {
            float mx = st[g][0][0];
#pragma unroll
            for (int n = 0; n < 4; n++)
#pragma unroll
                for (int r = 0; r < 4; r++) mx = fmaxf(mx, st[g][n][r]);
            mx = fmaxf(mx, __shfl_xor(mx, 16));
            mx = fmaxf(mx, __shfl_xor(mx, 32));
            const bool need = !__all(mx <= m[g] + 8.f);
            if (need) {
                const float mnew = fmaxf(m[g], mx);
                const float al = EXP2F(m[g] - mnew);
                m[g] = mnew;
                float alphaT[4];
#pragma unroll
                for (int r = 0; r < 4; r++) alphaT[r] = __shfl(al, quad * 4 + r);
#pragma unroll
                for (int dn = 0; dn < 4; dn++)
#pragma unroll
                    for (int r = 0; r < 4; r++) oacc[g][dn][r] *= alphaT[r];
#pragma unroll
                for (int r = 0; r < 4; r++) lacc[g][r] *= alphaT[r];
            }
#pragma unroll
            for (int n = 0; n < 4; n++)
#pragma unroll
                for (int r = 0; r < 4; r++)
                    st[g][n][r] = EXP2F(st[g][n][r] - m[g]);
        }

        // pack P fragments in-register (key permutation makes layout match)
        bf16x8 pf[2][2];
#pragma unroll
        for (int g = 0; g < 2; g++) {
            u32x4v w0, w1;
            w0[0] = pack_trunc(st[g][0][0], st[g][0][1]);
            w0[1] = pack_trunc(st[g][0][2], st[g][0][3]);
            w0[2] = pack_trunc(st[g][1][0], st[g][1][1]);
            w0[3] = pack_trunc(st[g][1][2], st[g][1][3]);
            w1[0] = pack_trunc(st[g][2][0], st[g][2][1]);
            w1[1] = pack_trunc(st[g][2][2], st[g][2][3]);
            w1[2] = pack_trunc(st[g][3][0], st[g][3][1]);
            w1[3] = pack_trunc(st[g][3][2], st[g][3][3]);
            pf[g][0] = __builtin_bit_cast(bf16x8, w0);
            pf[g][1] = __builtin_bit_cast(bf16x8, w1);
        }

        // l += rowsum(P) via MFMA (ones B-operand); O += P.V
        __builtin_amdgcn_s_setprio(1);
#pragma unroll
        for (int g = 0; g < 2; g++) {
            lacc[g] = __builtin_amdgcn_mfma_f32_16x16x32_bf16(pf[g][0], onesf, lacc[g], 0, 0, 0);
            lacc[g] = __builtin_amdgcn_mfma_f32_16x16x32_bf16(pf[g][1], onesf, lacc[g], 0, 0, 0);
        }
#pragma unroll
        for (int dn = 0; dn < 4; dn++) {
            const u16* vl = &Vs[(dn * 16 + mcol) * 64];
            bf16x8 vf0 = *(const bf16x8*)&vl[(quad ^ srd) << 3];
            bf16x8 vf1 = *(const bf16x8*)&vl[((quad | 4) ^ srd) << 3];
#pragma unroll
            for (int g = 0; g < 2; g++) {
                oacc[g][dn] = __builtin_amdgcn_mfma_f32_16x16x32_bf16(pf[g][0], vf0, oacc[g][dn], 0, 0, 0);
                oacc[g][dn] = __builtin_amdgcn_mfma_f32_16x16x32_bf16(pf[g][1], vf1, oacc[g][dn], 0, 0, 0);
            }
        }
        __builtin_amdgcn_s_setprio(0);
    }

    // normalize + write O (linv directly from lacc's row-layout; no shfl)
#pragma unroll
    for (int g = 0; g < 2; g++) {
        float linv[4];
#pragma unroll
        for (int r = 0; r < 4; r++) linv[r] = 1.f / lacc[g][r];
#pragma unroll
        for (int dn = 0; dn < 4; dn++)
#pragma unroll
            for (int r = 0; r < 4; r++) {
                const int row = wq0 + g * 16 + quad * 4 + r;
                o[((size_t)(b * S_ + row)) * D_ + h * DK_ + dn * 16 + mcol] =
                    f2bf(oacc[g][dn][r] * linv[r]);
            }
    }
}

// ---------------------------------------------------------------------------
extern "C" void kernel_launch(void* const* d_in, const int* in_sizes, int n_in,
                              void* d_out, int out_size, void* d_ws, size_t ws_size,
                              hipStream_t stream) {
    const float* x  = (const float*)d_in[0];
    const float* wq = (const float*)d_in[1];
    const float* wk = (const float*)d_in[2];
    const float* wv = (const float*)d_in[3];
    const float* wo = (const float*)d_in[4];
    const int*   tp = (const int*)d_in[5];
    float* out = (float*)d_out;

    u16* ws = (u16*)d_ws;
    const size_t NE = (size_t)M_ * D_;
    const size_t WE = (size_t)N_ * K_;
    u16* xb  = ws;
    u16* wqb = ws + NE;
    u16* wkb = wqb + WE;
    u16* wvb = wkb + WE;
    u16* wob = wvb + WE;
    u16* qb  = wob + WE;
    u16* kb  = qb + NE;
    u16* vtb = (u16*)d_out;   // V transposed [d][s], parked in fp32-sized d_out
    u16* ob  = xb;            // attention out aliases dead xb

    dim3 blk(256);
    cvt_all<<<dim3(12288), blk, 0, stream>>>(x, wq, wk, wv, wo,
                                             xb, wqb, wkb, wvb, wob);

    gemm_qkv_kernel<<<dim3(3 * (M_ / 128) * (N_ / 128)), blk, 0, stream>>>(
        xb, wqb, wkb, wvb, qb, kb, vtb);
    rope_qk<<<dim3((B_ * S_ * H_ * 4) / 256), blk, 0, stream>>>(qb, kb, tp);
    attn_kernel<<<dim3((S_ / 64) * H_ * B_), dim3(128), 0, stream>>>(qb, kb, vtb, ob);
    gemm_out_kernel<<<dim3((M_ / 128) * (N_ / 128)), blk, 0, stream>>>(ob, wob, out);
}

// Round 15
// 254.153 us; speedup vs baseline: 1.4087x; 1.4087x over previous
//
#include <hip/hip_runtime.h>

#define B_ 4
#define S_ 2048
#define D_ 1024
#define H_ 16
#define DK_ 64
#define M_ (B_*S_)   // 8192 rows
#define K_ D_        // 1024
#define N_ D_        // 1024
#define NSTEP 32     // K_/32

typedef unsigned short u16;
typedef unsigned int u32;
typedef __bf16 bf16x8 __attribute__((ext_vector_type(8)));
typedef float f32x4 __attribute__((ext_vector_type(4)));
typedef u32 u32x4v __attribute__((ext_vector_type(4)));

// native 2^x (v_exp_f32); '__exp2f' collides with glibc math.h macros
#define EXP2F(x) __builtin_amdgcn_exp2f(x)

__device__ __forceinline__ u16 f2bf(float f) {
    u32 u = __builtin_bit_cast(u32, f);
    u += 0x7fff + ((u >> 16) & 1);   // round-to-nearest-even
    return (u16)(u >> 16);
}
__device__ __forceinline__ float bf2f(u16 h) {
    u32 u = ((u32)h) << 16;
    return __builtin_bit_cast(float, u);
}
// truncation-packed bf16 pair (3 ops; P >= 0 -> bias < 2^-8 rel, OK for P)
__device__ __forceinline__ u32 pack_trunc(float a, float b) {
    return (__builtin_bit_cast(u32, a) >> 16) | (__builtin_bit_cast(u32, b) & 0xffff0000u);
}

#define GLDS16(g, l) __builtin_amdgcn_global_load_lds( \
    (__attribute__((address_space(1))) void*)(g),      \
    (__attribute__((address_space(3))) void*)(l), 16, 0, 0)

// ---------------------------------------------------------------------------
// fp32 -> bf16 convert, ALL 5 tensors in one dispatch (x + 4 weights).
// ---------------------------------------------------------------------------
__global__ __launch_bounds__(256) void cvt_all(
    const float* __restrict__ x,
    const float* __restrict__ w0, const float* __restrict__ w1,
    const float* __restrict__ w2, const float* __restrict__ w3,
    u16* __restrict__ xb,
    u16* __restrict__ o0, u16* __restrict__ o1,
    u16* __restrict__ o2, u16* __restrict__ o3) {
    const size_t i = (size_t)blockIdx.x * 256 + threadIdx.x;
    const float* in;
    u16* out;
    size_t off;
    if (i < 2097152) {
        in = x; out = xb; off = i;
    } else {
        const size_t j = i - 2097152;
        const int wi = (int)(j >> 18);
        off = j & 262143;
        in  = (wi == 0) ? w0 : (wi == 1) ? w1 : (wi == 2) ? w2 : w3;
        out = (wi == 0) ? o0 : (wi == 1) ? o1 : (wi == 2) ? o2 : o3;
    }
    const float4 f = *(const float4*)(in + off * 4);
    u32 p0 = (u32)f2bf(f.x) | ((u32)f2bf(f.y) << 16);
    u32 p1 = (u32)f2bf(f.z) | ((u32)f2bf(f.w) << 16);
    *(uint2*)(out + off * 4) = make_uint2(p0, p1);
}

// ---------------------------------------------------------------------------
// GEMM inner (3-buffer depth-2 counted-vmcnt — best of 5 measured variants:
// 71.4-73.3us qkv vs 75.0 2-phase, 78 2-buffer, 79.7 256²-8phase, 90 fused).
// Per step t: vmcnt(4) [stage(t) landed, stage(t+1) in flight] ->
// lgkmcnt(0) -> s_barrier -> issue stage(t+2) -> ds_read+MFMA buf[t%3].
// (kept: chunk XOR swizzle both-sides, T1 XCD remap, T5 setprio)
// MODE 0: bf16 C.  MODE 1: fp32 C.  MODE 2: bf16 V-transposed store.
// ---------------------------------------------------------------------------
template <int MODE>
__device__ __forceinline__ void gemm_tile3(const u16* __restrict__ A,
                                           const u16* __restrict__ Bm,
                                           void* __restrict__ Cv,
                                           int m0, int n0,
                                           u16* __restrict__ As,
                                           u16* __restrict__ Bs) {
    const int tid  = threadIdx.x;
    const int wave = tid >> 6, lane = tid & 63;
    const int wm = wave & 1, wn = wave >> 1;
    const int quad = lane >> 4, mcol = lane & 15;

    const int c0 = wave, c1 = wave + 4;
    const int r0 = c0 * 16 + (lane >> 2), r1 = c1 * 16 + (lane >> 2);
    const int kb = (((lane & 3) ^ ((lane >> 3) & 3)) * 8);   // pre-swizzled src chunk
    const u16* ga0 = A  + (size_t)(m0 + r0) * K_ + kb;
    const u16* ga1 = A  + (size_t)(m0 + r1) * K_ + kb;
    const u16* gb0 = Bm + (size_t)(n0 + r0) * K_ + kb;
    const u16* gb1 = Bm + (size_t)(n0 + r1) * K_ + kb;
    const int lo0 = c0 * 512, lo1 = c1 * 512;
    const int rsw = ((mcol >> 1) & 3);   // read-side chunk XOR

    f32x4 acc[4][4];
#pragma unroll
    for (int i = 0; i < 4; i++)
#pragma unroll
        for (int j = 0; j < 4; j++) acc[i][j] = f32x4{0.f, 0.f, 0.f, 0.f};

    // prologue: stage(0) -> buf0, stage(1) -> buf1 (8 loads in flight)
    GLDS16(ga0, As + lo0); GLDS16(ga1, As + lo1);
    GLDS16(gb0, Bs + lo0); GLDS16(gb1, Bs + lo1);
    ga0 += 32; ga1 += 32; gb0 += 32; gb1 += 32;
    GLDS16(ga0, As + 4096 + lo0); GLDS16(ga1, As + 4096 + lo1);
    GLDS16(gb0, Bs + 4096 + lo0); GLDS16(gb1, Bs + 4096 + lo1);
    ga0 += 32; ga1 += 32; gb0 += 32; gb1 += 32;

    int cur = 0, tgt = 2;
    for (int t = 0; t < NSTEP; ++t) {
        if (t < NSTEP - 1) asm volatile("s_waitcnt vmcnt(4)" ::: "memory");
        else               asm volatile("s_waitcnt vmcnt(0)" ::: "memory");
        asm volatile("s_waitcnt lgkmcnt(0)" ::: "memory");
        __builtin_amdgcn_s_barrier();

        if (t < NSTEP - 2) {
            u16* at = As + tgt * 4096;
            u16* bt = Bs + tgt * 4096;
            GLDS16(ga0, at + lo0); GLDS16(ga1, at + lo1);
            GLDS16(gb0, bt + lo0); GLDS16(gb1, bt + lo1);
            ga0 += 32; ga1 += 32; gb0 += 32; gb1 += 32;
        }

        const u16* Ab = As + cur * 4096;
        const u16* Bb = Bs + cur * 4096;
        bf16x8 af[4], bfr[4];
#pragma unroll
        for (int i = 0; i < 4; i++) {
            af[i]  = *(const bf16x8*)&Ab[(wm * 64 + i * 16 + mcol) * 32 + (quad ^ rsw) * 8];
            bfr[i] = *(const bf16x8*)&Bb[(wn * 64 + i * 16 + mcol) * 32 + (quad ^ rsw) * 8];
        }
        __builtin_amdgcn_s_setprio(1);
#pragma unroll
        for (int i = 0; i < 4; i++)
#pragma unroll
            for (int j = 0; j < 4; j++)
                acc[i][j] = __builtin_amdgcn_mfma_f32_16x16x32_bf16(
                    af[i], bfr[j], acc[i][j], 0, 0, 0);
        __builtin_amdgcn_s_setprio(0);

        cur = (cur == 2) ? 0 : cur + 1;
        tgt = (tgt == 2) ? 0 : tgt + 1;
    }

    // epilogue: C/D layout row=(lane>>4)*4+reg, col=lane&15
#pragma unroll
    for (int i = 0; i < 4; i++) {
        const int row = m0 + wm * 64 + i * 16 + quad * 4;
#pragma unroll
        for (int j = 0; j < 4; j++) {
            const int col = n0 + wn * 64 + j * 16 + mcol;
            if constexpr (MODE == 2) {
                const int hh = col >> 6, dd = col & 63;
                const int bb = row >> 11, ss = row & 2047;
                const u32 lo = (u32)f2bf(acc[i][j][0]) | ((u32)f2bf(acc[i][j][1]) << 16);
                const u32 hi = (u32)f2bf(acc[i][j][2]) | ((u32)f2bf(acc[i][j][3]) << 16);
                *(uint2*)((u16*)Cv + ((size_t)((bb * H_ + hh) * DK_ + dd)) * S_ + ss) =
                    make_uint2(lo, hi);
            } else {
#pragma unroll
                for (int r = 0; r < 4; r++) {
                    if constexpr (MODE == 1)
                        ((float*)Cv)[(size_t)(row + r) * N_ + col] = acc[i][j][r];
                    else
                        ((u16*)Cv)[(size_t)(row + r) * N_ + col] = f2bf(acc[i][j][r]);
                }
            }
        }
    }
}

// Q, K, V in one dispatch, flat 1536-block grid with XCD-aware remap (T1).
__global__ __launch_bounds__(256) void gemm_qkv_kernel(
    const u16* __restrict__ x,
    const u16* __restrict__ wq, const u16* __restrict__ wk,
    const u16* __restrict__ wv,
    u16* __restrict__ q, u16* __restrict__ k, u16* __restrict__ vt) {
    __shared__ u16 As[3 * 4096];
    __shared__ u16 Bs[3 * 4096];
    const int flat = blockIdx.x;
    const int w = (flat & 7) * 192 + (flat >> 3);
    const int my = w / 24;
    const int rem = w - my * 24;
    const int z = rem >> 3, nx = rem & 7;
    const int m0 = my * 128, n0 = nx * 128;
    if (z == 2) {
        gemm_tile3<2>(x, wv, vt, m0, n0, As, Bs);
    } else {
        const u16* Bm = z ? wk : wq;
        u16* C        = z ? k  : q;
        gemm_tile3<0>(x, Bm, C, m0, n0, As, Bs);
    }
}

// ---------------------------------------------------------------------------
// gemm_out: 2-phase 128², internal 32KB LDS (5 blocks/CU). Frozen.
// ---------------------------------------------------------------------------
__global__ __launch_bounds__(256) void gemm_out_kernel(
    const u16* __restrict__ o, const u16* __restrict__ wo, float* __restrict__ out) {
    __shared__ u16 As[2][128 * 32];
    __shared__ u16 Bs[2][128 * 32];
    const int flat = blockIdx.x;
    const int w = (flat & 7) * 64 + (flat >> 3);
    const int m0 = (w >> 3) * 128, n0 = (w & 7) * 128;

    const int tid  = threadIdx.x;
    const int wave = tid >> 6, lane = tid & 63;
    const int wm = wave & 1, wn = wave >> 1;
    const int quad = lane >> 4, mcol = lane & 15;

    const int c0 = wave, c1 = wave + 4;
    const int r0 = c0 * 16 + (lane >> 2), r1 = c1 * 16 + (lane >> 2);
    const int kb = (((lane & 3) ^ ((lane >> 3) & 3)) * 8);
    const u16* ga0 = o  + (size_t)(m0 + r0) * K_ + kb;
    const u16* ga1 = o  + (size_t)(m0 + r1) * K_ + kb;
    const u16* gb0 = wo + (size_t)(n0 + r0) * K_ + kb;
    const u16* gb1 = wo + (size_t)(n0 + r1) * K_ + kb;
    const int lo0 = c0 * 512, lo1 = c1 * 512;
    const int rsw = ((mcol >> 1) & 3);

    f32x4 acc[4][4];
#pragma unroll
    for (int i = 0; i < 4; i++)
#pragma unroll
        for (int j = 0; j < 4; j++) acc[i][j] = f32x4{0.f, 0.f, 0.f, 0.f};

    GLDS16(ga0, &As[0][lo0]); GLDS16(ga1, &As[0][lo1]);
    GLDS16(gb0, &Bs[0][lo0]); GLDS16(gb1, &Bs[0][lo1]);
    ga0 += 32; ga1 += 32; gb0 += 32; gb1 += 32;
    __syncthreads();

    for (int kt = 0; kt < K_; kt += 32) {
        const int cur = (kt >> 5) & 1;
        if (kt + 32 < K_) {
            const int nxt = cur ^ 1;
            GLDS16(ga0, &As[nxt][lo0]); GLDS16(ga1, &As[nxt][lo1]);
            GLDS16(gb0, &Bs[nxt][lo0]); GLDS16(gb1, &Bs[nxt][lo1]);
            ga0 += 32; ga1 += 32; gb0 += 32; gb1 += 32;
        }

        bf16x8 af[4], bfr[4];
#pragma unroll
        for (int i = 0; i < 4; i++) {
            af[i]  = *(const bf16x8*)&As[cur][(wm * 64 + i * 16 + mcol) * 32 + (quad ^ rsw) * 8];
            bfr[i] = *(const bf16x8*)&Bs[cur][(wn * 64 + i * 16 + mcol) * 32 + (quad ^ rsw) * 8];
        }
        __builtin_amdgcn_s_setprio(1);
#pragma unroll
        for (int i = 0; i < 4; i++)
#pragma unroll
            for (int j = 0; j < 4; j++)
                acc[i][j] = __builtin_amdgcn_mfma_f32_16x16x32_bf16(
                    af[i], bfr[j], acc[i][j], 0, 0, 0);
        __builtin_amdgcn_s_setprio(0);

        __syncthreads();
    }

#pragma unroll
    for (int i = 0; i < 4; i++) {
        const int row = m0 + wm * 64 + i * 16 + quad * 4;
#pragma unroll
        for (int j = 0; j < 4; j++) {
            const int col = n0 + wn * 64 + j * 16 + mcol;
#pragma unroll
            for (int r = 0; r < 4; r++)
                out[(size_t)(row + r) * N_ + col] = acc[i][j][r];
        }
    }
}

// ---------------------------------------------------------------------------
// RoPE (interleaved) in-place, vectorized (16 u16 / thread, uint4 ld/st).
// Q additionally scaled by log2(e)/8 (folds 1/sqrt(DK) + exp->exp2).
// ---------------------------------------------------------------------------
__global__ __launch_bounds__(256) void rope_qk(u16* __restrict__ q,
                                               u16* __restrict__ k,
                                               const int* __restrict__ pos) {
    const int idx = blockIdx.x * 256 + threadIdx.x;   // B*S*H*4 threads
    const int seg = idx & 3;
    const int h = (idx >> 2) & (H_ - 1);
    const int s = (idx >> 6) & (S_ - 1);
    const int b = idx >> 17;
    const float p = (float)pos[s];
    const float QSC = 0.18033688011112042f;   // log2(e)/sqrt(DK)
    const size_t off = ((size_t)(b * S_ + s)) * D_ + h * DK_ + seg * 16;

    u32 qa[8], ka[8];
    *(uint4*)&qa[0] = *(const uint4*)(q + off);
    *(uint4*)&qa[4] = *(const uint4*)(q + off + 8);
    *(uint4*)&ka[0] = *(const uint4*)(k + off);
    *(uint4*)&ka[4] = *(const uint4*)(k + off + 8);
#pragma unroll
    for (int w = 0; w < 8; w++) {
        const int i = seg * 8 + w;
        const float inv = exp2f((float)i * (-13.287712379549449f / 32.f));
        const float ang = p * inv;
        float sn, cs;
        __sincosf(ang, &sn, &cs);
        {
            const float x1 = bf2f((u16)(qa[w] & 0xffff));
            const float x2 = bf2f((u16)(qa[w] >> 16));
            qa[w] = (u32)f2bf((x1 * cs - x2 * sn) * QSC) |
                    ((u32)f2bf((x1 * sn + x2 * cs) * QSC) << 16);
        }
        {
            const float x1 = bf2f((u16)(ka[w] & 0xffff));
            const float x2 = bf2f((u16)(ka[w] >> 16));
            ka[w] = (u32)f2bf(x1 * cs - x2 * sn) |
                    ((u32)f2bf(x1 * sn + x2 * cs) << 16);
        }
    }
    *(uint4*)(q + off)     = *(uint4*)&qa[0];
    *(uint4*)(q + off + 8) = *(uint4*)&qa[4];
    *(uint4*)(k + off)     = *(uint4*)&ka[0];
    *(uint4*)(k + off + 8) = *(uint4*)&ka[4];
}

// ---------------------------------------------------------------------------
// Causal flash attention, MFMA, S^T formulation, exp2-domain softmax.
// R6 structure (the ONLY verified spill-free config: 256 threads, VGPR 108):
// key-permuted LDS, diagonal pairing qp<->15-qp, XOR swizzle both-sides,
// setprio, defer-max, MFMA ones-trick denominator. 64-row/128-thread
// variants spilled in R5 (VGPR 64, 477MB scratch) AND R13 (VGPR 96, 333MB).
// ---------------------------------------------------------------------------
__global__ __launch_bounds__(256) void attn_kernel(
    const u16* __restrict__ q, const u16* __restrict__ k,
    const u16* __restrict__ vt, u16* __restrict__ o) {
    __shared__ u16 Ks[64 * 64];      // [permuted key][d], XOR-swizzled
    __shared__ u16 Vs[64 * 64];      // [d][key] (natural key order), XOR-swizzled

    const int tid = threadIdx.x, wave = tid >> 6, lane = tid & 63;
    const int flat = blockIdx.x;
    const int qp = flat >> 6;                 // 0..7
    const int h = flat & (H_ - 1);
    const int b = (flat >> 4) & 3;
    const int quad = lane >> 4, mcol = lane & 15;
    const int srd = mcol & 7;                 // read-side swizzle

    const int rr2 = tid >> 2, cc2 = tid & 3;  // K/V staging coords
    const int sw = rr2 & 7;                   // write-side swizzle
    const int so0 = rr2 * 64 + (((cc2 * 2)     ^ sw) << 3);
    const int so1 = rr2 * 64 + (((cc2 * 2 + 1) ^ sw) << 3);
    // sigma(rr2): bits [5,1,0] keep, bits[3:2]->[4:3], bit[4]->[2]
    const int prr = (rr2 & 35) | ((rr2 & 12) << 1) | ((rr2 & 16) >> 2);
    const int ch2 = cc2 * 16;
    const u16* krow = k + ((size_t)(b * S_ + prr)) * D_ + h * DK_ + ch2;
    const u16* vrow = vt + ((size_t)((b * H_ + h) * DK_ + rr2)) * S_ + ch2;

    // ones B-operand for the l row-sum MFMA (bf16 1.0 = 0x3F80)
    u32x4v onesw;
    onesw[0] = onesw[1] = onesw[2] = onesw[3] = 0x3F803F80u;
    const bf16x8 onesf = __builtin_bit_cast(bf16x8, onesw);

    for (int pass = 0; pass < 2; pass++) {
        const int qt = pass ? (15 - qp) : qp;
        const int q0 = qt * 128;
        const int wq0 = q0 + wave * 32;
        const int jmax = 2 * qt + 1;

        // Q fragments straight from global
        bf16x8 qf[2][2];
#pragma unroll
        for (int g = 0; g < 2; g++) {
            const u16* qs = q + ((size_t)(b * S_ + wq0 + g * 16 + mcol)) * D_ + h * DK_ + quad * 8;
            qf[g][0] = *(const bf16x8*)qs;
            qf[g][1] = *(const bf16x8*)(qs + 32);
        }

        float m[2] = {-1e30f, -1e30f};
        f32x4 lacc[2];
        f32x4 oacc[2][4];
#pragma unroll
        for (int g = 0; g < 2; g++) {
            lacc[g] = f32x4{0.f, 0.f, 0.f, 0.f};
#pragma unroll
            for (int dn = 0; dn < 4; dn++) oacc[g][dn] = f32x4{0.f, 0.f, 0.f, 0.f};
        }

        uint4 kr0 = *(const uint4*)(krow);
        uint4 kr1 = *(const uint4*)(krow + 8);
        uint4 vr0 = *(const uint4*)(vrow);
        uint4 vr1 = *(const uint4*)(vrow + 8);

        for (int j = 0; j <= jmax; j++) {
            __syncthreads();
            *(uint4*)&Ks[so0] = kr0;
            *(uint4*)&Ks[so1] = kr1;
            *(uint4*)&Vs[so0] = vr0;
            *(uint4*)&Vs[so1] = vr1;
            __syncthreads();

            if (j < jmax) {
                kr0 = *(const uint4*)(krow + (size_t)(j + 1) * 64 * D_);
                kr1 = *(const uint4*)(krow + (size_t)(j + 1) * 64 * D_ + 8);
                vr0 = *(const uint4*)(vrow + (j + 1) * 64);
                vr1 = *(const uint4*)(vrow + (j + 1) * 64 + 8);
            }

            if (j * 64 > wq0 + 31) continue;   // fully masked for this wave

            // S^T = K.Q^T  (rows = permuted keys)
            f32x4 st[2][4];
            __builtin_amdgcn_s_setprio(1);
#pragma unroll
            for (int n = 0; n < 4; n++) {
                const u16* kl = &Ks[(n * 16 + mcol) * 64];
                bf16x8 kf0 = *(const bf16x8*)&kl[(quad ^ srd) << 3];
                bf16x8 kf1 = *(const bf16x8*)&kl[((quad | 4) ^ srd) << 3];
                f32x4 z0 = f32x4{0.f, 0.f, 0.f, 0.f};
                z0 = __builtin_amdgcn_mfma_f32_16x16x32_bf16(kf0, qf[0][0], z0, 0, 0, 0);
                z0 = __builtin_amdgcn_mfma_f32_16x16x32_bf16(kf1, qf[0][1], z0, 0, 0, 0);
                st[0][n] = z0;
                f32x4 z1 = f32x4{0.f, 0.f, 0.f, 0.f};
                z1 = __builtin_amdgcn_mfma_f32_16x16x32_bf16(kf0, qf[1][0], z1, 0, 0, 0);
                z1 = __builtin_amdgcn_mfma_f32_16x16x32_bf16(kf1, qf[1][1], z1, 0, 0, 0);
                st[1][n] = z1;
            }
            __builtin_amdgcn_s_setprio(0);

            // causal mask: st[g][n][r] is true key j*64 + 32*n1 + 8*quad + 4*n0 + r
            if (j * 64 + 63 > wq0) {
#pragma unroll
                for (int g = 0; g < 2; g++) {
                    const int qg = wq0 + g * 16 + mcol;
#pragma unroll
                    for (int n = 0; n < 4; n++) {
                        const int tb = j * 64 + ((n >> 1) << 5) + ((n & 1) << 2) + quad * 8;
#pragma unroll
                        for (int r = 0; r < 4; r++)
                            if (tb + r > qg) st[g][n][r] = -1e30f;
                    }
                }
            }

            // online softmax, exp2 domain, defer-max; sum offloaded to MFMA
#pragma unroll
            for (int g = 0; g < 2; g++) {
                float mx = st[g][0][0];
#pragma unroll
                for (int n = 0; n < 4; n++)
#pragma unroll
                    for (int r = 0; r < 4; r++) mx = fmaxf(mx, st[g][n][r]);
                mx = fmaxf(mx, __shfl_xor(mx, 16));
                mx = fmaxf(mx, __shfl_xor(mx, 32));
                const bool need = !__all(mx <= m[g] + 8.f);
                if (need) {
                    const float mnew = fmaxf(m[g], mx);
                    const float al = EXP2F(m[g] - mnew);
                    m[g] = mnew;
                    float alphaT[4];
#pragma unroll
                    for (int r = 0; r < 4; r++) alphaT[r] = __shfl(al, quad * 4 + r);
#pragma unroll
                    for (int dn = 0; dn < 4; dn++)
#pragma unroll
                        for (int r = 0; r < 4; r++) oacc[g][dn][r] *= alphaT[r];
#pragma unroll
                    for (int r = 0; r < 4; r++) lacc[g][r] *= alphaT[r];
                }
#pragma unroll
                for (int n = 0; n < 4; n++)
#pragma unroll
                    for (int r = 0; r < 4; r++)
                        st[g][n][r] = EXP2F(st[g][n][r] - m[g]);
            }

            // pack P fragments in-register (key permutation makes layout match)
            bf16x8 pf[2][2];
#pragma unroll
            for (int g = 0; g < 2; g++) {
                u32x4v w0, w1;
                w0[0] = pack_trunc(st[g][0][0], st[g][0][1]);
                w0[1] = pack_trunc(st[g][0][2], st[g][0][3]);
                w0[2] = pack_trunc(st[g][1][0], st[g][1][1]);
                w0[3] = pack_trunc(st[g][1][2], st[g][1][3]);
                w1[0] = pack_trunc(st[g][2][0], st[g][2][1]);
                w1[1] = pack_trunc(st[g][2][2], st[g][2][3]);
                w1[2] = pack_trunc(st[g][3][0], st[g][3][1]);
                w1[3] = pack_trunc(st[g][3][2], st[g][3][3]);
                pf[g][0] = __builtin_bit_cast(bf16x8, w0);
                pf[g][1] = __builtin_bit_cast(bf16x8, w1);
            }

            // l += rowsum(P) via MFMA (ones B-operand); O += P.V
            __builtin_amdgcn_s_setprio(1);
#pragma unroll
            for (int g = 0; g < 2; g++) {
                lacc[g] = __builtin_amdgcn_mfma_f32_16x16x32_bf16(pf[g][0], onesf, lacc[g], 0, 0, 0);
                lacc[g] = __builtin_amdgcn_mfma_f32_16x16x32_bf16(pf[g][1], onesf, lacc[g], 0, 0, 0);
            }
#pragma unroll
            for (int dn = 0; dn < 4; dn++) {
                const u16* vl = &Vs[(dn * 16 + mcol) * 64];
                bf16x8 vf0 = *(const bf16x8*)&vl[(quad ^ srd) << 3];
                bf16x8 vf1 = *(const bf16x8*)&vl[((quad | 4) ^ srd) << 3];
#pragma unroll
                for (int g = 0; g < 2; g++) {
                    oacc[g][dn] = __builtin_amdgcn_mfma_f32_16x16x32_bf16(pf[g][0], vf0, oacc[g][dn], 0, 0, 0);
                    oacc[g][dn] = __builtin_amdgcn_mfma_f32_16x16x32_bf16(pf[g][1], vf1, oacc[g][dn], 0, 0, 0);
                }
            }
            __builtin_amdgcn_s_setprio(0);
        }

        // normalize + write O (linv directly from lacc's row-layout; no shfl)
#pragma unroll
        for (int g = 0; g < 2; g++) {
            float linv[4];
#pragma unroll
            for (int r = 0; r < 4; r++) linv[r] = 1.f / lacc[g][r];
#pragma unroll
            for (int dn = 0; dn < 4; dn++)
#pragma unroll
                for (int r = 0; r < 4; r++) {
                    const int row = wq0 + g * 16 + quad * 4 + r;
                    o[((size_t)(b * S_ + row)) * D_ + h * DK_ + dn * 16 + mcol] =
                        f2bf(oacc[g][dn][r] * linv[r]);
                }
        }
    }
}

// ---------------------------------------------------------------------------
extern "C" void kernel_launch(void* const* d_in, const int* in_sizes, int n_in,
                              void* d_out, int out_size, void* d_ws, size_t ws_size,
                              hipStream_t stream) {
    const float* x  = (const float*)d_in[0];
    const float* wq = (const float*)d_in[1];
    const float* wk = (const float*)d_in[2];
    const float* wv = (const float*)d_in[3];
    const float* wo = (const float*)d_in[4];
    const int*   tp = (const int*)d_in[5];
    float* out = (float*)d_out;

    u16* ws = (u16*)d_ws;
    const size_t NE = (size_t)M_ * D_;
    const size_t WE = (size_t)N_ * K_;
    u16* xb  = ws;
    u16* wqb = ws + NE;
    u16* wkb = wqb + WE;
    u16* wvb = wkb + WE;
    u16* wob = wvb + WE;
    u16* qb  = wob + WE;
    u16* kb  = qb + NE;
    u16* vtb = (u16*)d_out;   // V transposed [d][s], parked in fp32-sized d_out
    u16* ob  = xb;            // attention out aliases dead xb

    dim3 blk(256);
    cvt_all<<<dim3(12288), blk, 0, stream>>>(x, wq, wk, wv, wo,
                                             xb, wqb, wkb, wvb, wob);

    gemm_qkv_kernel<<<dim3(3 * (M_ / 128) * (N_ / 128)), blk, 0, stream>>>(
        xb, wqb, wkb, wvb, qb, kb, vtb);
    rope_qk<<<dim3((B_ * S_ * H_ * 4) / 256), blk, 0, stream>>>(qb, kb, tp);
    attn_kernel<<<dim3((S_ / 128 / 2) * H_ * B_), blk, 0, stream>>>(qb, kb, vtb, ob);
    gemm_out_kernel<<<dim3((M_ / 128) * (N_ / 128)), blk, 0, stream>>>(ob, wob, out);
}